// Round 1
// baseline (296.133 us; speedup 1.0000x reference)
//
#include <hip/hip_runtime.h>

typedef unsigned short u16;
typedef unsigned int   u32;
typedef __bf16 bf16x8 __attribute__((ext_vector_type(8)));
typedef float  f32x4  __attribute__((ext_vector_type(4)));

__device__ __forceinline__ u16 f2bf(float f) {
  u32 u = __float_as_uint(f);
  u32 r = (u + 0x7fffu + ((u >> 16) & 1u)) >> 16;   // RNE
  return (u16)r;
}

typedef const __attribute__((address_space(1))) u32* gp1;
typedef __attribute__((address_space(3))) u32* lp3;
__device__ __forceinline__ void gload16(const void* g, void* l) {
  // per-lane global src; LDS dest = wave-uniform base + lane*16 (pass per-lane linear ptr)
  __builtin_amdgcn_global_load_lds((gp1)g, (lp3)l, 16, 0, 0);
}

__device__ __forceinline__ f32x4 mfma16(bf16x8 a, bf16x8 b, f32x4 c) {
  return __builtin_amdgcn_mfma_f32_16x16x32_bf16(a, b, c, 0, 0, 0);
}

// ---------------- cast fp32 -> bf16, 8 elems/thread ----------------
__global__ __launch_bounds__(256) void cast_bf16(const float* __restrict__ s,
                                                 u16* __restrict__ d, int n8) {
  int i = blockIdx.x * 256 + threadIdx.x;
  if (i >= n8) return;
  const float4* s4 = (const float4*)s;
  float4 a = s4[2 * i], b = s4[2 * i + 1];
  uint4 o;
  o.x = (u32)f2bf(a.x) | ((u32)f2bf(a.y) << 16);
  o.y = (u32)f2bf(a.z) | ((u32)f2bf(a.w) << 16);
  o.z = (u32)f2bf(b.x) | ((u32)f2bf(b.y) << 16);
  o.w = (u32)f2bf(b.z) | ((u32)f2bf(b.w) << 16);
  ((uint4*)d)[i] = o;
}

// ---------------- QKV GEMM: C(8192x2304) = Xb(8192x768) * Wqkv^T ----------------
// scatter epilogue into q/k/v [b,h,n,d] bf16, bias added, q scaled by 0.125
__global__ __launch_bounds__(256) void gemm_qkv(
    const u16* __restrict__ A, const u16* __restrict__ Bm,
    const float* __restrict__ bias,
    u16* __restrict__ Q, u16* __restrict__ K, u16* __restrict__ V) {
  __shared__ u16 As[128 * 32];
  __shared__ u16 Bs[128 * 32];
  const int tid = threadIdx.x, w = tid >> 6, l = tid & 63;
  const int lr = l & 15, lg = l >> 4;
  const int n0 = blockIdx.x * 128, m0 = blockIdx.y * 128;
  const int wr = (w >> 1) * 64, wc = (w & 1) * 64;
  f32x4 acc[4][4] = {};
  for (int kt = 0; kt < 768; kt += 32) {
    __syncthreads();
    const u16* Ab = A + m0 * 768 + kt;
    const u16* Bb = Bm + n0 * 768 + kt;
#pragma unroll
    for (int i = 0; i < 2; ++i) {
      int c = (i * 4 + w) * 64 + l;                       // chunk of 8 elems
      gload16(Ab + (c >> 2) * 768 + (c & 3) * 8, (char*)As + c * 16);
      gload16(Bb + (c >> 2) * 768 + (c & 3) * 8, (char*)Bs + c * 16);
    }
    __syncthreads();
    bf16x8 af[4], bfr[4];
#pragma unroll
    for (int m = 0; m < 4; ++m)
      af[m] = *(const bf16x8*)&As[(wr + m * 16 + lr) * 32 + lg * 8];
#pragma unroll
    for (int n = 0; n < 4; ++n)
      bfr[n] = *(const bf16x8*)&Bs[(wc + n * 16 + lr) * 32 + lg * 8];
#pragma unroll
    for (int m = 0; m < 4; ++m)
#pragma unroll
      for (int n = 0; n < 4; ++n) acc[m][n] = mfma16(af[m], bfr[n], acc[m][n]);
  }
#pragma unroll
  for (int n = 0; n < 4; ++n) {
    int f = n0 + wc + n * 16 + lr;
    float bv = bias[f];
    int three = f / 768;
    int hd = f - three * 768;
    int h = hd >> 6, dd = hd & 63;
    u16* dst = (three == 0) ? Q : (three == 1 ? K : V);
    float sc = (three == 0) ? 0.125f : 1.0f;
#pragma unroll
    for (int m = 0; m < 4; ++m) {
      int row0 = m0 + wr + m * 16 + lg * 4;
#pragma unroll
      for (int j = 0; j < 4; ++j) {
        int row = row0 + j;
        int b = row >> 11, ns = row & 2047;
        float val = (acc[m][n][j] + bv) * sc;
        dst[(((b * 12 + h) * 2048 + ns) << 6) + dd] = f2bf(val);
      }
    }
  }
}

// ---------------- flash attention, 128 q-rows/block, kv tiles of 128 ----------------
__global__ __launch_bounds__(256) void attn_kernel(
    const u16* __restrict__ Q, const u16* __restrict__ K,
    const u16* __restrict__ V, u16* __restrict__ O) {
  __shared__ u16 Qs[128 * 64];
  __shared__ u16 Ks[128 * 64];
  __shared__ u16 Vt[64 * 128];   // transposed: [d][kv]
  __shared__ u16 Ps[128 * 128];
  const int tid = threadIdx.x, w = tid >> 6, l = tid & 63;
  const int lr = l & 15, lg = l >> 4;
  int bi = blockIdx.x;
  int qt = bi & 15, h = (bi >> 4) % 12, b = bi / 192;
  const u16* Qp = Q + ((size_t)(b * 12 + h) * 2048 + qt * 128) * 64;
  const u16* Kp = K + (size_t)(b * 12 + h) * 2048 * 64;
  const u16* Vp = V + (size_t)(b * 12 + h) * 2048 * 64;
  u16* Op = O + (size_t)(b * 2048 + qt * 128) * 768 + h * 64;

#pragma unroll
  for (int i = 0; i < 4; ++i) {                 // stage Q once (linear 16KB)
    int c = (i * 4 + w) * 64 + l;
    gload16(Qp + c * 8, (char*)Qs + c * 16);
  }

  f32x4 aO[2][4] = {};
  f32x4 Mx[2], Ls[2];
#pragma unroll
  for (int mt = 0; mt < 2; ++mt)
#pragma unroll
    for (int j = 0; j < 4; ++j) { Mx[mt][j] = -1e30f; Ls[mt][j] = 0.0f; }

  for (int kt = 0; kt < 16; ++kt) {
    __syncthreads();                            // prev iter done with Ks/Vt/Ps
#pragma unroll
    for (int i = 0; i < 4; ++i) {               // stage K (linear)
      int c = (i * 4 + w) * 64 + l;
      gload16(Kp + kt * 8192 + c * 8, (char*)Ks + c * 16);
    }
#pragma unroll
    for (int i = 0; i < 4; ++i) {               // stage V transposed via regs
      int c = tid * 4 + i;
      uint4 dv = *(const uint4*)(Vp + kt * 8192 + c * 8);
      int n = c >> 3, d0 = (c & 7) * 8;
      u32 px;
      px = dv.x; Vt[(d0 + 0) * 128 + n] = (u16)px; Vt[(d0 + 1) * 128 + n] = (u16)(px >> 16);
      px = dv.y; Vt[(d0 + 2) * 128 + n] = (u16)px; Vt[(d0 + 3) * 128 + n] = (u16)(px >> 16);
      px = dv.z; Vt[(d0 + 4) * 128 + n] = (u16)px; Vt[(d0 + 5) * 128 + n] = (u16)(px >> 16);
      px = dv.w; Vt[(d0 + 6) * 128 + n] = (u16)px; Vt[(d0 + 7) * 128 + n] = (u16)(px >> 16);
    }
    __syncthreads();

    // S = Q*K^T  (each wave: 32 q-rows x 128 kv-cols)
    f32x4 S[2][8] = {};
#pragma unroll
    for (int ks = 0; ks < 2; ++ks) {
      bf16x8 aq[2];
      aq[0] = *(const bf16x8*)&Qs[(w * 32 + 0 + lr) * 64 + ks * 32 + lg * 8];
      aq[1] = *(const bf16x8*)&Qs[(w * 32 + 16 + lr) * 64 + ks * 32 + lg * 8];
#pragma unroll
      for (int nt = 0; nt < 8; ++nt) {
        bf16x8 bk = *(const bf16x8*)&Ks[(nt * 16 + lr) * 64 + ks * 32 + lg * 8];
        S[0][nt] = mfma16(aq[0], bk, S[0][nt]);
        S[1][nt] = mfma16(aq[1], bk, S[1][nt]);
      }
    }

    // online softmax (rows live in 16-lane groups; reduce via shfl_xor width 16)
#pragma unroll
    for (int mt = 0; mt < 2; ++mt) {
      f32x4 tmax = S[mt][0];
#pragma unroll
      for (int nt = 1; nt < 8; ++nt)
#pragma unroll
        for (int j = 0; j < 4; ++j) tmax[j] = fmaxf(tmax[j], S[mt][nt][j]);
#pragma unroll
      for (int msk = 1; msk < 16; msk <<= 1)
#pragma unroll
        for (int j = 0; j < 4; ++j)
          tmax[j] = fmaxf(tmax[j], __shfl_xor(tmax[j], msk, 16));
      f32x4 mnew, sc;
#pragma unroll
      for (int j = 0; j < 4; ++j) {
        mnew[j] = fmaxf(Mx[mt][j], tmax[j]);
        sc[j] = __expf(Mx[mt][j] - mnew[j]);
      }
      f32x4 rsum = {};
#pragma unroll
      for (int nt = 0; nt < 8; ++nt) {
        int colb = nt * 16 + lr;
#pragma unroll
        for (int j = 0; j < 4; ++j) {
          float p = __expf(S[mt][nt][j] - mnew[j]);
          rsum[j] += p;
          Ps[(w * 32 + mt * 16 + lg * 4 + j) * 128 + colb] = f2bf(p);
        }
      }
#pragma unroll
      for (int msk = 1; msk < 16; msk <<= 1)
#pragma unroll
        for (int j = 0; j < 4; ++j) rsum[j] += __shfl_xor(rsum[j], msk, 16);
#pragma unroll
      for (int j = 0; j < 4; ++j) {
        Ls[mt][j] = Ls[mt][j] * sc[j] + rsum[j];
        Mx[mt][j] = mnew[j];
      }
#pragma unroll
      for (int dt = 0; dt < 4; ++dt) aO[mt][dt] *= sc;
    }
    __syncthreads();                            // Ps/Vt ready for PV

    // O += P*V
#pragma unroll
    for (int ks = 0; ks < 4; ++ks) {
      bf16x8 ap[2];
      ap[0] = *(const bf16x8*)&Ps[(w * 32 + 0 + lr) * 128 + ks * 32 + lg * 8];
      ap[1] = *(const bf16x8*)&Ps[(w * 32 + 16 + lr) * 128 + ks * 32 + lg * 8];
#pragma unroll
      for (int dt = 0; dt < 4; ++dt) {
        bf16x8 bv = *(const bf16x8*)&Vt[(dt * 16 + lr) * 128 + ks * 32 + lg * 8];
        aO[0][dt] = mfma16(ap[0], bv, aO[0][dt]);
        aO[1][dt] = mfma16(ap[1], bv, aO[1][dt]);
      }
    }
  }

#pragma unroll
  for (int mt = 0; mt < 2; ++mt)
#pragma unroll
    for (int dt = 0; dt < 4; ++dt)
#pragma unroll
      for (int j = 0; j < 4; ++j) {
        int row = w * 32 + mt * 16 + lg * 4 + j;
        float val = aO[mt][dt][j] / Ls[mt][j];
        Op[(size_t)row * 768 + dt * 16 + lr] = f2bf(val);
      }
}

// ---------------- out GEMM: C(8192x768) = Ob(8192x768) * Wout^T + b, fp32 out ----------------
__global__ __launch_bounds__(256) void gemm_out(
    const u16* __restrict__ A, const u16* __restrict__ Bm,
    const float* __restrict__ bias, float* __restrict__ C) {
  __shared__ u16 As[128 * 32];
  __shared__ u16 Bs[128 * 32];
  const int tid = threadIdx.x, w = tid >> 6, l = tid & 63;
  const int lr = l & 15, lg = l >> 4;
  const int n0 = blockIdx.x * 128, m0 = blockIdx.y * 128;
  const int wr = (w >> 1) * 64, wc = (w & 1) * 64;
  f32x4 acc[4][4] = {};
  for (int kt = 0; kt < 768; kt += 32) {
    __syncthreads();
    const u16* Ab = A + m0 * 768 + kt;
    const u16* Bb = Bm + n0 * 768 + kt;
#pragma unroll
    for (int i = 0; i < 2; ++i) {
      int c = (i * 4 + w) * 64 + l;
      gload16(Ab + (c >> 2) * 768 + (c & 3) * 8, (char*)As + c * 16);
      gload16(Bb + (c >> 2) * 768 + (c & 3) * 8, (char*)Bs + c * 16);
    }
    __syncthreads();
    bf16x8 af[4], bfr[4];
#pragma unroll
    for (int m = 0; m < 4; ++m)
      af[m] = *(const bf16x8*)&As[(wr + m * 16 + lr) * 32 + lg * 8];
#pragma unroll
    for (int n = 0; n < 4; ++n)
      bfr[n] = *(const bf16x8*)&Bs[(wc + n * 16 + lr) * 32 + lg * 8];
#pragma unroll
    for (int m = 0; m < 4; ++m)
#pragma unroll
      for (int n = 0; n < 4; ++n) acc[m][n] = mfma16(af[m], bfr[n], acc[m][n]);
  }
#pragma unroll
  for (int n = 0; n < 4; ++n) {
    int f = n0 + wc + n * 16 + lr;
    float bv = bias[f];
#pragma unroll
    for (int m = 0; m < 4; ++m) {
      int row0 = m0 + wr + m * 16 + lg * 4;
#pragma unroll
      for (int j = 0; j < 4; ++j) {
        int row = row0 + j;
        C[(size_t)row * 768 + f] = acc[m][n][j] + bv;
      }
    }
  }
}

extern "C" void kernel_launch(void* const* d_in, const int* in_sizes, int n_in,
                              void* d_out, int out_size, void* d_ws, size_t ws_size,
                              hipStream_t stream) {
  const float* x     = (const float*)d_in[0];
  const float* w_qkv = (const float*)d_in[1];
  const float* b_qkv = (const float*)d_in[2];
  const float* w_out = (const float*)d_in[3];
  const float* b_out = (const float*)d_in[4];

  char* ws = (char*)d_ws;
  u16* xb    = (u16*)(ws + 0);          // 8192x768        12,582,912 B
  u16* wqkvb = (u16*)(ws + 12582912);   // 2304x768         3,538,944 B
  u16* wob   = (u16*)(ws + 16121856);   // 768x768          1,179,648 B
  u16* qb    = (u16*)(ws + 17301504);   // [b,h,n,d]       12,582,912 B
  u16* kb    = (u16*)(ws + 29884416);
  u16* vb    = (u16*)(ws + 42467328);
  u16* ob    = (u16*)(ws + 55050240);   // [b,n,h*64+d]    12,582,912 B  (total ~67.6 MB)

  cast_bf16<<<786432 / 256, 256, 0, stream>>>(x, xb, 786432);
  cast_bf16<<<221184 / 256, 256, 0, stream>>>(w_qkv, wqkvb, 221184);
  cast_bf16<<<73728 / 256, 256, 0, stream>>>(w_out, wob, 73728);

  gemm_qkv<<<dim3(18, 64), 256, 0, stream>>>(xb, wqkvb, b_qkv, qb, kb, vb);
  attn_kernel<<<768, 256, 0, stream>>>(qb, kb, vb, ob);
  gemm_out<<<dim3(6, 64), 256, 0, stream>>>(ob, wob, b_out, (float*)d_out);
}